// Round 20
// baseline (132.668 us; speedup 1.0000x reference)
//
#include <hip/hip_runtime.h>
#include <float.h>

#define N_ROWS 131072
#define DIM 64
#define KCODES 1024
#define TAU_HALF 5.0e-4f              // tau=1e-3 in s-space; m-space gap = s-gap/2
#define NBLOCKA (N_ROWS / 128)        // 1024 blocks, 4 waves x 32 rows each
#define NPART (NBLOCKA * 4)           // 4096 loss partials (one per scorer wave)

typedef __attribute__((ext_vector_type(8))) short short8;
typedef __attribute__((ext_vector_type(4))) float f32x4;

// bf16 round-to-nearest-even split helpers
__device__ __forceinline__ unsigned short f2bf_rne(float x) {
    unsigned int u = __float_as_uint(x);
    unsigned int r = u + 0x7FFFu + ((u >> 16) & 1u);
    return (unsigned short)(r >> 16);
}
__device__ __forceinline__ float bf2f(unsigned short h) {
    return __uint_as_float(((unsigned int)h) << 16);
}

// numpy pairwise sum of squares over 64 contiguous floats (bit-exact vs
// np.sum(v*v, axis=-1)): fp32 products, 8 strided accumulators, tree combine.
__device__ __forceinline__ float np_pairwise_sq64(const float* v) {
    float r[8];
#pragma unroll
    for (int j = 0; j < 8; ++j) r[j] = __fmul_rn(v[j], v[j]);
#pragma unroll
    for (int i = 8; i < 64; i += 8)
#pragma unroll
        for (int j = 0; j < 8; ++j)
            r[j] = __fadd_rn(r[j], __fmul_rn(v[i + j], v[i + j]));
    return __fadd_rn(
        __fadd_rn(__fadd_rn(r[0], r[1]), __fadd_rn(r[2], r[3])),
        __fadd_rn(__fadd_rn(r[4], r[5]), __fadd_rn(r[6], r[7])));
}

// streamed variant (no 64-reg array): same bit-exact numpy scheme
__device__ __forceinline__ float np_sq_stream(const float* xr) {
    float r[8];
    {
        float4 a = *reinterpret_cast<const float4*>(xr);
        float4 b = *reinterpret_cast<const float4*>(xr + 4);
        r[0] = __fmul_rn(a.x, a.x); r[1] = __fmul_rn(a.y, a.y);
        r[2] = __fmul_rn(a.z, a.z); r[3] = __fmul_rn(a.w, a.w);
        r[4] = __fmul_rn(b.x, b.x); r[5] = __fmul_rn(b.y, b.y);
        r[6] = __fmul_rn(b.z, b.z); r[7] = __fmul_rn(b.w, b.w);
    }
#pragma unroll
    for (int i = 8; i < 64; i += 8) {
        float4 a = *reinterpret_cast<const float4*>(xr + i);
        float4 b = *reinterpret_cast<const float4*>(xr + i + 4);
        r[0] = __fadd_rn(r[0], __fmul_rn(a.x, a.x));
        r[1] = __fadd_rn(r[1], __fmul_rn(a.y, a.y));
        r[2] = __fadd_rn(r[2], __fmul_rn(a.z, a.z));
        r[3] = __fadd_rn(r[3], __fmul_rn(a.w, a.w));
        r[4] = __fadd_rn(r[4], __fmul_rn(b.x, b.x));
        r[5] = __fadd_rn(r[5], __fmul_rn(b.y, b.y));
        r[6] = __fadd_rn(r[6], __fmul_rn(b.z, b.z));
        r[7] = __fadd_rn(r[7], __fmul_rn(b.w, b.w));
    }
    return __fadd_rn(
        __fadd_rn(__fadd_rn(r[0], r[1]), __fadd_rn(r[2], r[3])),
        __fadd_rn(__fadd_rn(r[4], r[5]), __fadd_rn(r[6], r[7])));
}

// exact reference-chain distance, streamed:
// d = fl32( fl32(a_sq - fl32(2*dot_f64)) + b_sq )   [validated rounds 3-18]
__device__ __forceinline__ float np_dist_stream(const float* xr, const float* e,
                                                float a_sq, float bq) {
    double acc0 = 0.0, acc1 = 0.0, acc2 = 0.0, acc3 = 0.0;
#pragma unroll
    for (int d = 0; d < DIM; d += 4) {
        float4 ev = *reinterpret_cast<const float4*>(e + d);
        float4 xv = *reinterpret_cast<const float4*>(xr + d);
        acc0 = fma((double)xv.x, (double)ev.x, acc0);
        acc1 = fma((double)xv.y, (double)ev.y, acc1);
        acc2 = fma((double)xv.z, (double)ev.z, acc2);
        acc3 = fma((double)xv.w, (double)ev.w, acc3);
    }
    double dot = (acc0 + acc1) + (acc2 + acc3);
    float ab = (float)(2.0 * dot);
    return __fadd_rn(__fsub_rn(a_sq, ab), bq);
}

// ---------------------------------------------------------------------------
// Prep (64 blocks x 256): 16 threads per code; each packs one 8-element
// k-group (hi or lo) as a single 16B short8 store into MFMA frag order.
// sub==0 thread also computes np-exact b_sq.
// ---------------------------------------------------------------------------
__global__ __launch_bounds__(256, 4)
void vq_prep(const float* __restrict__ emb,
             float* __restrict__ bsqf,
             unsigned short* __restrict__ epack) {
    const int tid = blockIdx.x * 256 + threadIdx.x;   // 0..16383
    const int c   = tid >> 4;        // 0..1023
    const int sub = tid & 15;
    const int g   = sub & 7;         // k-group (8 elements)
    const int lvl = sub >> 3;        // 0=hi, 1=lo

    const float* e8 = emb + (size_t)c * DIM + g * 8;
    float4 v0 = *reinterpret_cast<const float4*>(e8);
    float4 v1 = *reinterpret_cast<const float4*>(e8 + 4);
    float ev[8] = {v0.x, v0.y, v0.z, v0.w, v1.x, v1.y, v1.z, v1.w};
    short8 outv;
#pragma unroll
    for (int j = 0; j < 8; ++j) {
        unsigned short hh = f2bf_rne(ev[j]);
        outv[j] = (lvl == 0) ? (short)hh : (short)f2bf_rne(ev[j] - bf2f(hh));
    }
    const size_t base =
        ((((size_t)(c >> 4) * 2 + lvl) * 2 + (g >> 2)) * 64 +
         (((g & 3) << 4) | (c & 15))) * 8;
    *reinterpret_cast<short8*>(epack + base) = outv;

    if (sub == 0) {
        float e[DIM];
        const float4* src = reinterpret_cast<const float4*>(emb + (size_t)c * DIM);
#pragma unroll
        for (int i = 0; i < DIM / 4; ++i) {
            float4 v = src[i];
            e[i * 4 + 0] = v.x; e[i * 4 + 1] = v.y;
            e[i * 4 + 2] = v.z; e[i * 4 + 3] = v.w;
        }
        bsqf[c] = np_pairwise_sq64(e);
    }
}

// ---------------------------------------------------------------------------
// Pass A (fused): MFMA scorer (round-12 core, bq-in-accumulator) + inline
// exact resolution of flagged rows + block-local streaming tail.
// Tail: 1KB fully-contiguous bursts; qout via NON-TEMPORAL stores (write-once
// data must not evict x/epack from L2/L3). NO device atomics in this kernel.
// ---------------------------------------------------------------------------
__global__ __launch_bounds__(256, 4)
void vq_fast(const float* __restrict__ x,
             const float* __restrict__ emb,
             const unsigned short* __restrict__ epack,
             const float* __restrict__ bsqf,
             float* __restrict__ idxout,
             float* __restrict__ qout,
             float* __restrict__ partials) {
    __shared__ unsigned short lds[16384];   // 32 KiB = 8 code-tiles (reused as ldsK)
    __shared__ float bql[KCODES];           // 4 KiB bsq table
    __shared__ float aql[4][2][16];         // a_sq per (wave, mf, row-in-frag)

    const int t = threadIdx.x;
    const int lane = t & 63;
    const int wid = t >> 6;
    const int rowbase = blockIdx.x * 128 + wid * 32;
    const int arow = lane & 15;
    const int kgrp = lane >> 4;

    // stage bsq table (reads happen after the chunk-0 barriers)
#pragma unroll
    for (int i = 0; i < 4; ++i) bql[t + i * 256] = bsqf[t + i * 256];

    // A-frags: 2 M-frags x 2 k-tiles, hi+lo; exact fp32 a_sq alongside
    short8 ah[2][2], al[2][2];
#pragma unroll
    for (int mf = 0; mf < 2; ++mf) {
        float ssq = 0.f;
#pragma unroll
        for (int kt = 0; kt < 2; ++kt) {
            const float* src = x + (size_t)(rowbase + mf * 16 + arow) * DIM + kt * 32 + kgrp * 8;
            float4 v0 = *reinterpret_cast<const float4*>(src);
            float4 v1 = *reinterpret_cast<const float4*>(src + 4);
            float xv[8] = {v0.x, v0.y, v0.z, v0.w, v1.x, v1.y, v1.z, v1.w};
            short8 h, l;
#pragma unroll
            for (int j = 0; j < 8; ++j) {
                unsigned short hh = f2bf_rne(xv[j]);
                h[j] = (short)hh;
                l[j] = (short)f2bf_rne(xv[j] - bf2f(hh));
                ssq = fmaf(xv[j], xv[j], ssq);
            }
            ah[mf][kt] = h;
            al[mf][kt] = l;
        }
        // reduce over the 4 kgrp lanes holding this row's 4 k-slices
        ssq += __shfl_xor(ssq, 16);
        ssq += __shfl_xor(ssq, 32);
        if (kgrp == 0) aql[wid][mf][arow] = ssq;
    }

    float best[2][4], sec[2][4];
    int bidx[2][4], sidx[2][4];
#pragma unroll
    for (int mf = 0; mf < 2; ++mf)
#pragma unroll
        for (int r = 0; r < 4; ++r) {
            best[mf][r] = -FLT_MAX; sec[mf][r] = -FLT_MAX;
            bidx[mf][r] = 0; sidx[mf][r] = 0;
        }

    for (int ch = 0; ch < 8; ++ch) {
        __syncthreads();
        {   // stage 32KB chunk: 2048 float4, 8 per thread, coalesced
            const float4* gsrc = reinterpret_cast<const float4*>(epack + (size_t)ch * 16384);
            float4* ldst = reinterpret_cast<float4*>(lds);
#pragma unroll
            for (int i = 0; i < 8; ++i)
                ldst[t + i * 256] = gsrc[t + i * 256];
        }
        __syncthreads();

        for (int ctl = 0; ctl < 8; ++ctl) {
            const int code0 = (ch * 8 + ctl) * 16;
            const unsigned short* fb = lds + ctl * 2048 + lane * 8;
            short8 bh0 = *reinterpret_cast<const short8*>(fb + 0 * 512);
            short8 bh1 = *reinterpret_cast<const short8*>(fb + 1 * 512);
            short8 bl0 = *reinterpret_cast<const short8*>(fb + 2 * 512);
            short8 bl1 = *reinterpret_cast<const short8*>(fb + 3 * 512);
            const float nb = -0.5f * bql[code0 + arow];   // C-init = -bq/2

            f32x4 acc[2];
#pragma unroll
            for (int mf = 0; mf < 2; ++mf) {
                f32x4 a = {nb, nb, nb, nb};
                a = __builtin_amdgcn_mfma_f32_16x16x32_bf16(ah[mf][0], bh0, a, 0, 0, 0);
                a = __builtin_amdgcn_mfma_f32_16x16x32_bf16(ah[mf][1], bh1, a, 0, 0, 0);
                a = __builtin_amdgcn_mfma_f32_16x16x32_bf16(ah[mf][0], bl0, a, 0, 0, 0);
                a = __builtin_amdgcn_mfma_f32_16x16x32_bf16(ah[mf][1], bl1, a, 0, 0, 0);
                a = __builtin_amdgcn_mfma_f32_16x16x32_bf16(al[mf][0], bh0, a, 0, 0, 0);
                a = __builtin_amdgcn_mfma_f32_16x16x32_bf16(al[mf][1], bh1, a, 0, 0, 0);
                acc[mf] = a;
            }

            const int code = code0 + arow;   // C col = lane&15 [m89/m91]
#pragma unroll
            for (int mf = 0; mf < 2; ++mf)
#pragma unroll
                for (int r = 0; r < 4; ++r) {
                    float m = acc[mf][r];            // bigger = closer
                    bool gt_b = m > best[mf][r];
                    bool gt_s = m > sec[mf][r];
                    sec[mf][r]  = gt_b ? best[mf][r] : (gt_s ? m : sec[mf][r]);
                    sidx[mf][r] = gt_b ? bidx[mf][r] : (gt_s ? code : sidx[mf][r]);
                    best[mf][r] = gt_b ? m : best[mf][r];
                    bidx[mf][r] = gt_b ? code : bidx[mf][r];
                }
        }
    }

    // cross-lane top-2 merge (max semantics) over the 16 col-classes
#pragma unroll
    for (int mf = 0; mf < 2; ++mf)
#pragma unroll
        for (int r = 0; r < 4; ++r) {
            float b = best[mf][r], sc = sec[mf][r];
            int bi = bidx[mf][r], si = sidx[mf][r];
#pragma unroll
            for (int off = 1; off < 16; off <<= 1) {
                float ob  = __shfl_xor(b, off);
                int   obi = __shfl_xor(bi, off);
                float osc = __shfl_xor(sc, off);
                int   osi = __shfl_xor(si, off);
                bool o_gt = ob > b;
                float loser  = o_gt ? b  : ob;
                int   loseri = o_gt ? bi : obi;
                b  = o_gt ? ob  : b;
                bi = o_gt ? obi : bi;
                float ns = sc; int nsi = si;
                if (osc > ns)   { ns = osc;   nsi = osi; }
                if (loser > ns) { ns = loser; nsi = loseri; }
                sc = ns; si = nsi;
            }
            best[mf][r] = b; sec[mf][r] = sc;
            bidx[mf][r] = bi; sidx[mf][r] = si;
        }

    __syncthreads();   // all LDS chunk reads done; safe to reuse lds as ldsK
    int* ldsK = reinterpret_cast<int*>(lds);

    if ((lane & 15) == 0) {
        const int rgrp = lane >> 4;   // C row = (lane>>4)*4 + reg [m89/m91]
        float lsum = 0.f;
#pragma unroll
        for (int mf = 0; mf < 2; ++mf)
#pragma unroll
            for (int r = 0; r < 4; ++r) {
                int rl = rgrp * 4 + r;
                int rloc = wid * 32 + mf * 16 + rl;      // row within block
                int bi = bidx[mf][r], si = sidx[mf][r];
                int k = bi;
                if (best[mf][r] - sec[mf][r] <= TAU_HALF) {
                    // inline exact resolution (validated np chain; bql = exact bsq)
                    int c1 = min(bi, si), c2 = max(bi, si);
                    const float* xr = x + (size_t)(rowbase - wid * 32 + rloc) * DIM;
                    float a_sq = np_sq_stream(xr);
                    float d1 = np_dist_stream(xr, emb + (size_t)c1 * DIM, a_sq, bql[c1]);
                    float d2 = np_dist_stream(xr, emb + (size_t)c2 * DIM, a_sq, bql[c2]);
                    k = (d2 < d1) ? c2 : c1;   // tie -> lower index (c1)
                }
                ldsK[rloc] = k;
                // loss_row = a_sq - 2*m_best  (= a_sq - 2ab + b_sq)
                lsum += fmaf(-2.0f, best[mf][r], aql[wid][mf][rl]);
            }
        // reduce the 4 writer lanes (0,16,32,48) -> lane 0
        lsum += __shfl_xor(lsum, 16);
        lsum += __shfl_xor(lsum, 32);
        if (lane == 0) partials[blockIdx.x * 4 + wid] = lsum;  // plain store
    }
    __syncthreads();

    // streaming tail (coalesced, non-temporal): wave covers its 32 rows (8KB)
    // in 8 instructions; per instruction lane l writes bytes [l*16, l*16+16)
    // of a 1KB segment (= 4 rows). NT stores keep qout out of L2/L3.
    // ext-vector f32x4 pointers (nontemporal builtin rejects HIP float4 class).
    const int blkrow0 = blockIdx.x * 128;
#pragma unroll
    for (int i = 0; i < 8; ++i) {
        int seg_row = wid * 32 + i * 4 + (lane >> 4);   // row within block
        int k = ldsK[seg_row];
        const f32x4* er = reinterpret_cast<const f32x4*>(emb + (size_t)k * DIM) + (lane & 15);
        f32x4* qr = reinterpret_cast<f32x4*>(qout + (size_t)(blkrow0 + seg_row) * DIM) + (lane & 15);
        f32x4 v = *er;
        __builtin_nontemporal_store(v, qr);
    }
    // idxout: one thread per row (tiny traffic); hist derived later from idxout
    if (t < 128) {
        int k = ldsK[t];
        idxout[blkrow0 + t] = (float)k;
    }
}

// ---------------------------------------------------------------------------
// Final (1 block x 1024): build hist from idxout via LDS histogram (no
// device-scope atomics anywhere), then perplexity (fp64) + loss tree over
// the 4096 scorer-wave partials.
// ---------------------------------------------------------------------------
__global__ __launch_bounds__(1024, 1)
void vq_final(const float* __restrict__ idxout,
              const float* __restrict__ partials,
              float* __restrict__ out2) {
    __shared__ int shist[KCODES];
    __shared__ double sh[KCODES];
    __shared__ double sl[KCODES];
    const int t = threadIdx.x;

    shist[t] = 0;
    __syncthreads();

    // LDS histogram: coalesced reads, 128 per thread
#pragma unroll 4
    for (int i = 0; i < N_ROWS / 1024; ++i) {
        int k = (int)idxout[t + i * 1024];
        atomicAdd(&shist[k], 1);
    }
    __syncthreads();

    double p = (double)shist[t] * (1.0 / (double)N_ROWS);
    sh[t] = p * log(p + 1e-10);

    double ls = 0.0;
#pragma unroll
    for (int i = 0; i < NPART / KCODES; ++i)   // 4 each
        ls += (double)partials[t + i * KCODES];
    sl[t] = ls;
    __syncthreads();

    for (int off = KCODES / 2; off > 0; off >>= 1) {
        if (t < off) { sh[t] += sh[t + off]; sl[t] += sl[t + off]; }
        __syncthreads();
    }
    if (t == 0) {
        out2[0] = (float)exp(-sh[0]);
        out2[1] = (float)(1.25 * sl[0] * (1.0 / (double)((size_t)N_ROWS * DIM)));
    }
}

// ---------------------------------------------------------------------------
extern "C" void kernel_launch(void* const* d_in, const int* in_sizes, int n_in,
                              void* d_out, int out_size, void* d_ws, size_t ws_size,
                              hipStream_t stream) {
    const float* x   = (const float*)d_in[0];   // [131072, 64]
    const float* emb = (const float*)d_in[1];   // [1024, 64]
    float* out = (float*)d_out;

    // ws: bsqf[1024]@0 | partials[4096]@4096 (16KB) | epack@36864 (256KB)
    float* bsqf      = (float*)d_ws;
    float* partials  = (float*)((char*)d_ws + 4096);
    unsigned short* epack = (unsigned short*)((char*)d_ws + 36864);

    float* qout    = out;                       // 8388608
    float* idxout  = out + 8388608;             // 131072
    float* scalars = out + 8388608 + 131072;    // perplexity, vq_loss

    vq_prep <<<64, 256, 0, stream>>>(emb, bsqf, epack);
    vq_fast <<<NBLOCKA, 256, 0, stream>>>(x, emb, epack, bsqf, idxout, qout,
                                          partials);
    vq_final<<<1, 1024, 0, stream>>>(idxout, partials, scalars);
}

// Round 21
// 103.359 us; speedup vs baseline: 1.2836x; 1.2836x over previous
//
#include <hip/hip_runtime.h>
#include <float.h>

#define N_ROWS 131072
#define DIM 64
#define KCODES 1024
#define TAU_HALF 5.0e-4f              // tau=1e-3 in s-space; m-space gap = s-gap/2
#define NBLOCKA (N_ROWS / 128)        // 1024 blocks, 4 waves x 32 rows each
#define NPART (NBLOCKA * 4)           // 4096 loss partials (one per scorer wave)

typedef __attribute__((ext_vector_type(8))) short short8;
typedef __attribute__((ext_vector_type(4))) float f32x4;

// bf16 round-to-nearest-even split helpers
__device__ __forceinline__ unsigned short f2bf_rne(float x) {
    unsigned int u = __float_as_uint(x);
    unsigned int r = u + 0x7FFFu + ((u >> 16) & 1u);
    return (unsigned short)(r >> 16);
}
__device__ __forceinline__ float bf2f(unsigned short h) {
    return __uint_as_float(((unsigned int)h) << 16);
}

// numpy pairwise sum of squares over 64 contiguous floats (bit-exact vs
// np.sum(v*v, axis=-1)): fp32 products, 8 strided accumulators, tree combine.
__device__ __forceinline__ float np_pairwise_sq64(const float* v) {
    float r[8];
#pragma unroll
    for (int j = 0; j < 8; ++j) r[j] = __fmul_rn(v[j], v[j]);
#pragma unroll
    for (int i = 8; i < 64; i += 8)
#pragma unroll
        for (int j = 0; j < 8; ++j)
            r[j] = __fadd_rn(r[j], __fmul_rn(v[i + j], v[i + j]));
    return __fadd_rn(
        __fadd_rn(__fadd_rn(r[0], r[1]), __fadd_rn(r[2], r[3])),
        __fadd_rn(__fadd_rn(r[4], r[5]), __fadd_rn(r[6], r[7])));
}

// streamed variant (no 64-reg array): same bit-exact numpy scheme
__device__ __forceinline__ float np_sq_stream(const float* xr) {
    float r[8];
    {
        float4 a = *reinterpret_cast<const float4*>(xr);
        float4 b = *reinterpret_cast<const float4*>(xr + 4);
        r[0] = __fmul_rn(a.x, a.x); r[1] = __fmul_rn(a.y, a.y);
        r[2] = __fmul_rn(a.z, a.z); r[3] = __fmul_rn(a.w, a.w);
        r[4] = __fmul_rn(b.x, b.x); r[5] = __fmul_rn(b.y, b.y);
        r[6] = __fmul_rn(b.z, b.z); r[7] = __fmul_rn(b.w, b.w);
    }
#pragma unroll
    for (int i = 8; i < 64; i += 8) {
        float4 a = *reinterpret_cast<const float4*>(xr + i);
        float4 b = *reinterpret_cast<const float4*>(xr + i + 4);
        r[0] = __fadd_rn(r[0], __fmul_rn(a.x, a.x));
        r[1] = __fadd_rn(r[1], __fmul_rn(a.y, a.y));
        r[2] = __fadd_rn(r[2], __fmul_rn(a.z, a.z));
        r[3] = __fadd_rn(r[3], __fmul_rn(a.w, a.w));
        r[4] = __fadd_rn(r[4], __fmul_rn(b.x, b.x));
        r[5] = __fadd_rn(r[5], __fmul_rn(b.y, b.y));
        r[6] = __fadd_rn(r[6], __fmul_rn(b.z, b.z));
        r[7] = __fadd_rn(r[7], __fmul_rn(b.w, b.w));
    }
    return __fadd_rn(
        __fadd_rn(__fadd_rn(r[0], r[1]), __fadd_rn(r[2], r[3])),
        __fadd_rn(__fadd_rn(r[4], r[5]), __fadd_rn(r[6], r[7])));
}

// exact reference-chain distance, streamed:
// d = fl32( fl32(a_sq - fl32(2*dot_f64)) + b_sq )   [validated rounds 3-18]
__device__ __forceinline__ float np_dist_stream(const float* xr, const float* e,
                                                float a_sq, float bq) {
    double acc0 = 0.0, acc1 = 0.0, acc2 = 0.0, acc3 = 0.0;
#pragma unroll
    for (int d = 0; d < DIM; d += 4) {
        float4 ev = *reinterpret_cast<const float4*>(e + d);
        float4 xv = *reinterpret_cast<const float4*>(xr + d);
        acc0 = fma((double)xv.x, (double)ev.x, acc0);
        acc1 = fma((double)xv.y, (double)ev.y, acc1);
        acc2 = fma((double)xv.z, (double)ev.z, acc2);
        acc3 = fma((double)xv.w, (double)ev.w, acc3);
    }
    double dot = (acc0 + acc1) + (acc2 + acc3);
    float ab = (float)(2.0 * dot);
    return __fadd_rn(__fsub_rn(a_sq, ab), bq);
}

// ---------------------------------------------------------------------------
// Prep (64 blocks x 256): 16 threads per code; each packs one 8-element
// k-group (hi or lo) as a single 16B short8 store into MFMA frag order.
// sub==0 thread also computes np-exact b_sq and zeroes hist.
// ---------------------------------------------------------------------------
__global__ __launch_bounds__(256, 4)
void vq_prep(const float* __restrict__ emb,
             int* __restrict__ hist,
             float* __restrict__ bsqf,
             unsigned short* __restrict__ epack) {
    const int tid = blockIdx.x * 256 + threadIdx.x;   // 0..16383
    const int c   = tid >> 4;        // 0..1023
    const int sub = tid & 15;
    const int g   = sub & 7;         // k-group (8 elements)
    const int lvl = sub >> 3;        // 0=hi, 1=lo

    const float* e8 = emb + (size_t)c * DIM + g * 8;
    float4 v0 = *reinterpret_cast<const float4*>(e8);
    float4 v1 = *reinterpret_cast<const float4*>(e8 + 4);
    float ev[8] = {v0.x, v0.y, v0.z, v0.w, v1.x, v1.y, v1.z, v1.w};
    short8 outv;
#pragma unroll
    for (int j = 0; j < 8; ++j) {
        unsigned short hh = f2bf_rne(ev[j]);
        outv[j] = (lvl == 0) ? (short)hh : (short)f2bf_rne(ev[j] - bf2f(hh));
    }
    const size_t base =
        ((((size_t)(c >> 4) * 2 + lvl) * 2 + (g >> 2)) * 64 +
         (((g & 3) << 4) | (c & 15))) * 8;
    *reinterpret_cast<short8*>(epack + base) = outv;

    if (sub == 0) {
        float e[DIM];
        const float4* src = reinterpret_cast<const float4*>(emb + (size_t)c * DIM);
#pragma unroll
        for (int i = 0; i < DIM / 4; ++i) {
            float4 v = src[i];
            e[i * 4 + 0] = v.x; e[i * 4 + 1] = v.y;
            e[i * 4 + 2] = v.z; e[i * 4 + 3] = v.w;
        }
        bsqf[c] = np_pairwise_sq64(e);
        hist[c] = 0;
    }
}

// ---------------------------------------------------------------------------
// Pass A (fused): MFMA scorer (round-12 core, bq-in-accumulator) + inline
// exact resolution of flagged rows + block-local streaming tail.
// Tail: per instruction, lane l writes bytes [l*16, l*16+16) of a 1KB
// segment (= 4 rows) -> fully-coalesced 1KB stores. (Round-18 config —
// best measured; NT stores and atomic-free variants disproven in r19-20.)
// ---------------------------------------------------------------------------
__global__ __launch_bounds__(256, 4)
void vq_fast(const float* __restrict__ x,
             const float* __restrict__ emb,
             const unsigned short* __restrict__ epack,
             const float* __restrict__ bsqf,
             float* __restrict__ idxout,
             float* __restrict__ qout,
             int* __restrict__ hist,
             float* __restrict__ partials) {
    __shared__ unsigned short lds[16384];   // 32 KiB = 8 code-tiles (reused as ldsK)
    __shared__ float bql[KCODES];           // 4 KiB bsq table
    __shared__ float aql[4][2][16];         // a_sq per (wave, mf, row-in-frag)

    const int t = threadIdx.x;
    const int lane = t & 63;
    const int wid = t >> 6;
    const int rowbase = blockIdx.x * 128 + wid * 32;
    const int arow = lane & 15;
    const int kgrp = lane >> 4;

    // stage bsq table (reads happen after the chunk-0 barriers)
#pragma unroll
    for (int i = 0; i < 4; ++i) bql[t + i * 256] = bsqf[t + i * 256];

    // A-frags: 2 M-frags x 2 k-tiles, hi+lo; exact fp32 a_sq alongside
    short8 ah[2][2], al[2][2];
#pragma unroll
    for (int mf = 0; mf < 2; ++mf) {
        float ssq = 0.f;
#pragma unroll
        for (int kt = 0; kt < 2; ++kt) {
            const float* src = x + (size_t)(rowbase + mf * 16 + arow) * DIM + kt * 32 + kgrp * 8;
            float4 v0 = *reinterpret_cast<const float4*>(src);
            float4 v1 = *reinterpret_cast<const float4*>(src + 4);
            float xv[8] = {v0.x, v0.y, v0.z, v0.w, v1.x, v1.y, v1.z, v1.w};
            short8 h, l;
#pragma unroll
            for (int j = 0; j < 8; ++j) {
                unsigned short hh = f2bf_rne(xv[j]);
                h[j] = (short)hh;
                l[j] = (short)f2bf_rne(xv[j] - bf2f(hh));
                ssq = fmaf(xv[j], xv[j], ssq);
            }
            ah[mf][kt] = h;
            al[mf][kt] = l;
        }
        // reduce over the 4 kgrp lanes holding this row's 4 k-slices
        ssq += __shfl_xor(ssq, 16);
        ssq += __shfl_xor(ssq, 32);
        if (kgrp == 0) aql[wid][mf][arow] = ssq;
    }

    float best[2][4], sec[2][4];
    int bidx[2][4], sidx[2][4];
#pragma unroll
    for (int mf = 0; mf < 2; ++mf)
#pragma unroll
        for (int r = 0; r < 4; ++r) {
            best[mf][r] = -FLT_MAX; sec[mf][r] = -FLT_MAX;
            bidx[mf][r] = 0; sidx[mf][r] = 0;
        }

    for (int ch = 0; ch < 8; ++ch) {
        __syncthreads();
        {   // stage 32KB chunk: 2048 float4, 8 per thread, coalesced
            const float4* gsrc = reinterpret_cast<const float4*>(epack + (size_t)ch * 16384);
            float4* ldst = reinterpret_cast<float4*>(lds);
#pragma unroll
            for (int i = 0; i < 8; ++i)
                ldst[t + i * 256] = gsrc[t + i * 256];
        }
        __syncthreads();

        for (int ctl = 0; ctl < 8; ++ctl) {
            const int code0 = (ch * 8 + ctl) * 16;
            const unsigned short* fb = lds + ctl * 2048 + lane * 8;
            short8 bh0 = *reinterpret_cast<const short8*>(fb + 0 * 512);
            short8 bh1 = *reinterpret_cast<const short8*>(fb + 1 * 512);
            short8 bl0 = *reinterpret_cast<const short8*>(fb + 2 * 512);
            short8 bl1 = *reinterpret_cast<const short8*>(fb + 3 * 512);
            const float nb = -0.5f * bql[code0 + arow];   // C-init = -bq/2

            f32x4 acc[2];
#pragma unroll
            for (int mf = 0; mf < 2; ++mf) {
                f32x4 a = {nb, nb, nb, nb};
                a = __builtin_amdgcn_mfma_f32_16x16x32_bf16(ah[mf][0], bh0, a, 0, 0, 0);
                a = __builtin_amdgcn_mfma_f32_16x16x32_bf16(ah[mf][1], bh1, a, 0, 0, 0);
                a = __builtin_amdgcn_mfma_f32_16x16x32_bf16(ah[mf][0], bl0, a, 0, 0, 0);
                a = __builtin_amdgcn_mfma_f32_16x16x32_bf16(ah[mf][1], bl1, a, 0, 0, 0);
                a = __builtin_amdgcn_mfma_f32_16x16x32_bf16(al[mf][0], bh0, a, 0, 0, 0);
                a = __builtin_amdgcn_mfma_f32_16x16x32_bf16(al[mf][1], bh1, a, 0, 0, 0);
                acc[mf] = a;
            }

            const int code = code0 + arow;   // C col = lane&15 [m89/m91]
#pragma unroll
            for (int mf = 0; mf < 2; ++mf)
#pragma unroll
                for (int r = 0; r < 4; ++r) {
                    float m = acc[mf][r];            // bigger = closer
                    bool gt_b = m > best[mf][r];
                    bool gt_s = m > sec[mf][r];
                    sec[mf][r]  = gt_b ? best[mf][r] : (gt_s ? m : sec[mf][r]);
                    sidx[mf][r] = gt_b ? bidx[mf][r] : (gt_s ? code : sidx[mf][r]);
                    best[mf][r] = gt_b ? m : best[mf][r];
                    bidx[mf][r] = gt_b ? code : bidx[mf][r];
                }
        }
    }

    // cross-lane top-2 merge (max semantics) over the 16 col-classes
#pragma unroll
    for (int mf = 0; mf < 2; ++mf)
#pragma unroll
        for (int r = 0; r < 4; ++r) {
            float b = best[mf][r], sc = sec[mf][r];
            int bi = bidx[mf][r], si = sidx[mf][r];
#pragma unroll
            for (int off = 1; off < 16; off <<= 1) {
                float ob  = __shfl_xor(b, off);
                int   obi = __shfl_xor(bi, off);
                float osc = __shfl_xor(sc, off);
                int   osi = __shfl_xor(si, off);
                bool o_gt = ob > b;
                float loser  = o_gt ? b  : ob;
                int   loseri = o_gt ? bi : obi;
                b  = o_gt ? ob  : b;
                bi = o_gt ? obi : bi;
                float ns = sc; int nsi = si;
                if (osc > ns)   { ns = osc;   nsi = osi; }
                if (loser > ns) { ns = loser; nsi = loseri; }
                sc = ns; si = nsi;
            }
            best[mf][r] = b; sec[mf][r] = sc;
            bidx[mf][r] = bi; sidx[mf][r] = si;
        }

    __syncthreads();   // all LDS chunk reads done; safe to reuse lds as ldsK
    int* ldsK = reinterpret_cast<int*>(lds);

    if ((lane & 15) == 0) {
        const int rgrp = lane >> 4;   // C row = (lane>>4)*4 + reg [m89/m91]
        float lsum = 0.f;
#pragma unroll
        for (int mf = 0; mf < 2; ++mf)
#pragma unroll
            for (int r = 0; r < 4; ++r) {
                int rl = rgrp * 4 + r;
                int rloc = wid * 32 + mf * 16 + rl;      // row within block
                int bi = bidx[mf][r], si = sidx[mf][r];
                int k = bi;
                if (best[mf][r] - sec[mf][r] <= TAU_HALF) {
                    // inline exact resolution (validated np chain; bql = exact bsq)
                    int c1 = min(bi, si), c2 = max(bi, si);
                    const float* xr = x + (size_t)(rowbase - wid * 32 + rloc) * DIM;
                    float a_sq = np_sq_stream(xr);
                    float d1 = np_dist_stream(xr, emb + (size_t)c1 * DIM, a_sq, bql[c1]);
                    float d2 = np_dist_stream(xr, emb + (size_t)c2 * DIM, a_sq, bql[c2]);
                    k = (d2 < d1) ? c2 : c1;   // tie -> lower index (c1)
                }
                ldsK[rloc] = k;
                // loss_row = a_sq - 2*m_best  (= a_sq - 2ab + b_sq)
                lsum += fmaf(-2.0f, best[mf][r], aql[wid][mf][rl]);
            }
        // reduce the 4 writer lanes (0,16,32,48) -> lane 0
        lsum += __shfl_xor(lsum, 16);
        lsum += __shfl_xor(lsum, 32);
        if (lane == 0) partials[blockIdx.x * 4 + wid] = lsum;  // plain store
    }
    __syncthreads();

    // streaming tail (coalesced): wave covers its 32 rows (8KB) in 8
    // instructions; per instruction lane l writes bytes [l*16, l*16+16) of a
    // 1KB segment (= 4 rows) -> every store is a full 1KB contiguous burst.
    const int blkrow0 = blockIdx.x * 128;
#pragma unroll
    for (int i = 0; i < 8; ++i) {
        int seg_row = wid * 32 + i * 4 + (lane >> 4);   // row within block
        int k = ldsK[seg_row];
        const float4* er = reinterpret_cast<const float4*>(emb + (size_t)k * DIM) + (lane & 15);
        float4* qr = reinterpret_cast<float4*>(qout + (size_t)(blkrow0 + seg_row) * DIM) + (lane & 15);
        *qr = *er;
    }
    // idxout + hist: one thread per row (tiny traffic)
    if (t < 128) {
        int k = ldsK[t];
        idxout[blkrow0 + t] = (float)k;
        atomicAdd(&hist[k], 1);
    }
}

// ---------------------------------------------------------------------------
// Final: perplexity (fp64) from hist + deterministic loss tree over the
// 4096 scorer-wave partials.
// ---------------------------------------------------------------------------
__global__ void vq_final(const int* __restrict__ hist,
                         const float* __restrict__ partials,
                         float* __restrict__ out2) {
    __shared__ double sh[KCODES];
    __shared__ double sl[KCODES];
    int t = threadIdx.x;

    double p = (double)hist[t] * (1.0 / (double)N_ROWS);
    sh[t] = p * log(p + 1e-10);

    double ls = 0.0;
#pragma unroll
    for (int i = 0; i < NPART / KCODES; ++i)   // 4 each
        ls += (double)partials[t + i * KCODES];
    sl[t] = ls;
    __syncthreads();

    for (int off = KCODES / 2; off > 0; off >>= 1) {
        if (t < off) { sh[t] += sh[t + off]; sl[t] += sl[t + off]; }
        __syncthreads();
    }
    if (t == 0) {
        out2[0] = (float)exp(-sh[0]);
        out2[1] = (float)(1.25 * sl[0] * (1.0 / (double)((size_t)N_ROWS * DIM)));
    }
}

// ---------------------------------------------------------------------------
extern "C" void kernel_launch(void* const* d_in, const int* in_sizes, int n_in,
                              void* d_out, int out_size, void* d_ws, size_t ws_size,
                              hipStream_t stream) {
    const float* x   = (const float*)d_in[0];   // [131072, 64]
    const float* emb = (const float*)d_in[1];   // [1024, 64]
    float* out = (float*)d_out;

    // ws: hist[1024]@0 | bsqf@4096 | partials[4096]@8192 (16KB) |
    //     epack@40960 (256KB) — total ~297KB
    int*   hist      = (int*)d_ws;
    float* bsqf      = (float*)((char*)d_ws + 4096);
    float* partials  = (float*)((char*)d_ws + 8192);
    unsigned short* epack = (unsigned short*)((char*)d_ws + 40960);

    float* qout    = out;                       // 8388608
    float* idxout  = out + 8388608;             // 131072
    float* scalars = out + 8388608 + 131072;    // perplexity, vq_loss

    vq_prep <<<64, 256, 0, stream>>>(emb, hist, bsqf, epack);
    vq_fast <<<NBLOCKA, 256, 0, stream>>>(x, emb, epack, bsqf, idxout, qout,
                                          hist, partials);
    vq_final<<<1, KCODES, 0, stream>>>(hist, partials, scalars);
}